// Round 9
// baseline (201.707 us; speedup 1.0000x reference)
//
#include <hip/hip_runtime.h>

// KNN argmin over L2, round 9: fused prep + parity-pipelined phase A.
//  - k_prep (S only): LDS tile -> Sh/Sl MFMA-panel bf16 split + S_T + sqS
//    in one pass. Q needs NO prep: phase A builds Q-fragments from fp32 Q
//    in-kernel (one-time per wave) with the same hi/lo RNE split.
//  - k_phaseA: R8's panel-swizzled loads (TA fix, proven 1.8x) + two
//    accumulator parities so the epilogue of step N-1 overlaps the MFMAs
//    of steps N/N+1 (R8 showed MfmaUtil+VALUBusy ~= 100%: anti-overlap).
//  - k_phaseB: unchanged exact fp32 rescore (C~1 blocks/query at EPS=0.05).
//
// Filter certification unchanged: 3-term split (sh.qh + sl.qh + sh.ql),
// key error <= ~0.014 << EPS=0.05 => rescore set provably contains the
// true first-argmin support. Phase B strict-< ascending + lexicographic
// cross-lane on exact fp32 keys => np.argmin first-index semantics.

#define NTOT   16384
#define DIM    64
#define SBLK   256                // bmin granularity
#define NSB    (NTOT / SBLK)      // 64
#define EPS    0.05f
#define FLT_BIG 3.4e38f

typedef __attribute__((ext_vector_type(8))) short short8;
typedef __attribute__((ext_vector_type(4))) float float4v;

__device__ __forceinline__ ushort bf16_rne(float x) {
  unsigned u = __float_as_uint(x);
  return (ushort)((u + 0x7FFF + ((u >> 16) & 1)) >> 16);
}

// ---------------------------------------------------------------------------
// Fused S prep: panel-swizzled bf16 hi/lo + transpose + row sum-of-squares.
// Panel layout (16-row panels, matches phase A lane order, proven in R8):
//   off(r,k) = (r>>4)*1024 + (k>>5)*512 + (((k&31)>>3)*16 + (r&15))*8 + (k&7)
__global__ __launch_bounds__(256) void k_prep(
    const float* __restrict__ S, ushort* __restrict__ Sh,
    ushort* __restrict__ Sl, float* __restrict__ S_T,
    float* __restrict__ sqS) {
  __shared__ float tile[64][65];
  const int tid = threadIdx.x;
  const int tx = tid & 63;
  const int ty = tid >> 6;
  const int rbase = blockIdx.x * 64;

#pragma unroll
  for (int i = 0; i < 16; ++i) {
    const int r = i * 4 + ty;
    tile[r][tx] = S[(size_t)(rbase + r) * DIM + tx];  // coalesced
  }
  __syncthreads();

  // Transposed copy (coalesced stores, conflict-free via +1 pad).
#pragma unroll
  for (int i = 0; i < 16; ++i) {
    const int d = i * 4 + ty;
    S_T[(size_t)d * NTOT + rbase + tx] = tile[tx][d];
  }

  // Panel-swizzled bf16 hi/lo. Thread -> 2 slots x 8 k-elements; stores are
  // lane-contiguous 16B (fully coalesced).
  const int panel = tid >> 6;           // 0..3 (16-row panel in this block)
  const int half = (tid >> 5) & 1;      // k-half (k>=32)
  const int slot0 = (tid & 31) * 2;     // slot = q8*16 + m, q8 in [0,4)
#pragma unroll
  for (int ss = 0; ss < 2; ++ss) {
    const int s = slot0 + ss;
    const int m = s & 15;
    const int q8 = s >> 4;
    const int row = panel * 16 + m;
    const int kb = half * 32 + q8 * 8;
    short8 hv, lv;
#pragma unroll
    for (int j = 0; j < 8; ++j) {
      const float x = tile[row][kb + j];
      const ushort h = bf16_rne(x);
      const float hf = __uint_as_float(((unsigned)h) << 16);
      hv[j] = (short)h;
      lv[j] = (short)bf16_rne(x - hf);
    }
    const size_t goff =
        (size_t)((rbase >> 4) + panel) * 1024 + (size_t)half * 512 + (size_t)s * 8;
    *(short8*)&Sh[goff] = hv;
    *(short8*)&Sl[goff] = lv;
  }

  // Row sum of squares.
  if (tid < 64) {
    float acc = 0.0f;
#pragma unroll
    for (int d = 0; d < DIM; ++d) {
      const float v = tile[tid][d];
      acc = fmaf(v, v, acc);
    }
    sqS[rbase + tid] = acc;
  }
}

// ---------------------------------------------------------------------------
// Phase A: block = 4 waves; wave w: 64 queries x 512 supports.
// grid = (8 splits, 256 q-tiles). A = supports (M), B = queries (N),
// 16x16x32 bf16; layouts HW-verified R4-R8. All S-fragment loads are
// lane-contiguous 1KB wave loads (panel storage). Q-fragments built
// in-kernel from fp32 Q (hi/lo RNE split, one-time).

#define MFMA16(A, B, C) __builtin_amdgcn_mfma_f32_16x16x32_bf16(A, B, C, 0, 0, 0)

// 24 MFMA for one 16-support step into parity accs PH/PL.
#define MFMA_STEP(H0, H1, L0, L1, PH, PL)                                  \
  do {                                                                     \
    _Pragma("unroll")                                                      \
    for (int t = 0; t < 4; ++t) {                                          \
      float4v xh = {0.f, 0.f, 0.f, 0.f};                                   \
      float4v xl = {0.f, 0.f, 0.f, 0.f};                                   \
      xh = MFMA16(H0, qh[t][0], xh);                                       \
      xl = MFMA16(H0, qlo[t][0], xl);                                      \
      xh = MFMA16(H1, qh[t][1], xh);                                       \
      xl = MFMA16(H1, qlo[t][1], xl);                                      \
      xh = MFMA16(L0, qh[t][0], xh);                                       \
      xh = MFMA16(L1, qh[t][1], xh);                                       \
      PH[t] = xh;                                                          \
      PL[t] = xl;                                                          \
    }                                                                      \
  } while (0)

// key = |s|^2 - 2(hi_terms + lo_term); fold into running block-min.
#define EPILOGUE(PH, PL, SQ)                                               \
  do {                                                                     \
    _Pragma("unroll")                                                      \
    for (int t = 0; t < 4; ++t) {                                          \
      const float k0 = fmaf(-2.f, PH[t][0], fmaf(-2.f, PL[t][0], SQ.x));   \
      const float k1 = fmaf(-2.f, PH[t][1], fmaf(-2.f, PL[t][1], SQ.y));   \
      const float k2 = fmaf(-2.f, PH[t][2], fmaf(-2.f, PL[t][2], SQ.z));   \
      const float k3 = fmaf(-2.f, PH[t][3], fmaf(-2.f, PL[t][3], SQ.w));   \
      bmr[t] = fminf(bmr[t], fminf(fminf(k0, k1), fminf(k2, k3)));         \
    }                                                                      \
  } while (0)

__global__ __launch_bounds__(256, 2) void k_phaseA(
    const ushort* __restrict__ Sh, const ushort* __restrict__ Sl,
    const float* __restrict__ Q, const float* __restrict__ sqS,
    float* __restrict__ bmin) {
  const int tid = threadIdx.x;
  const int l = tid & 63;
  const int w = tid >> 6;
  const int lm = l & 15;
  const int lq = l >> 4;
  const int split = blockIdx.x;       // 0..7
  const int qbase = blockIdx.y * 64;
  const int sbase = split * 2048 + w * 512;

  // Q (B) fragments from fp32 Q, hi/lo split in-register. One-time cost.
  short8 qh[4][2], qlo[4][2];
#pragma unroll
  for (int t = 0; t < 4; ++t) {
    const float* qrow = Q + (size_t)(qbase + t * 16 + lm) * DIM + lq * 8;
#pragma unroll
    for (int kc = 0; kc < 2; ++kc) {
      float x[8];
      *(float4*)&x[0] = *(const float4*)(qrow + kc * 32);
      *(float4*)&x[4] = *(const float4*)(qrow + kc * 32 + 4);
      short8 hv, lv;
#pragma unroll
      for (int j = 0; j < 8; ++j) {
        const ushort h = bf16_rne(x[j]);
        const float hf = __uint_as_float(((unsigned)h) << 16);
        hv[j] = (short)h;
        lv[j] = (short)bf16_rne(x[j] - hf);
      }
      qh[t][kc] = hv;
      qlo[t][kc] = lv;
    }
  }

  const ushort* pSh = Sh + (size_t)(sbase >> 4) * 1024 + (size_t)l * 8;
  const ushort* pSl = Sl + (size_t)(sbase >> 4) * 1024 + (size_t)l * 8;
  const float* psq = sqS + sbase + lq * 4;

  // Double-buffered S fragments (a = even steps, b = odd steps).
  short8 h0a = *(const short8*)(pSh);
  short8 h1a = *(const short8*)(pSh + 512);
  short8 l0a = *(const short8*)(pSl);
  short8 l1a = *(const short8*)(pSl + 512);
  float4 sqa = *(const float4*)(psq);
  short8 h0b = *(const short8*)(pSh + 1024);
  short8 h1b = *(const short8*)(pSh + 1024 + 512);
  short8 l0b = *(const short8*)(pSl + 1024);
  short8 l1b = *(const short8*)(pSl + 1024 + 512);
  float4 sqb = *(const float4*)(psq + 16);

  float4v P0[4], P1[4], L0acc[4], L1acc[4];
  float bmr[4] = {FLT_BIG, FLT_BIG, FLT_BIG, FLT_BIG};

  // Prologue: step 0 MFMAs into parity 0; refill buffer a for step 2.
  MFMA_STEP(h0a, h1a, l0a, l1a, P0, L0acc);
  {
    h0a = *(const short8*)(pSh + 2048);
    h1a = *(const short8*)(pSh + 2048 + 512);
    l0a = *(const short8*)(pSl + 2048);
    l1a = *(const short8*)(pSl + 2048 + 512);
  }

  for (int st = 1; st < 32; st += 2) {
    // Odd step st: MFMAs (buffer b) -> parity 1.
    MFMA_STEP(h0b, h1b, l0b, l1b, P1, L1acc);
    // Epilogue for even step st-1 overlaps in-flight MFMAs.
    EPILOGUE(P0, L0acc, sqa);
    sqa = *(const float4*)(psq + (st + 1) * 16);  // sq for even step st+1
    if (st + 2 < 32) {  // refill b for step st+2
      const int off = (st + 2) * 1024;
      h0b = *(const short8*)(pSh + off);
      h1b = *(const short8*)(pSh + off + 512);
      l0b = *(const short8*)(pSl + off);
      l1b = *(const short8*)(pSl + off + 512);
    }
    // Even step st+1: MFMAs (buffer a) -> parity 0.
    if (st + 1 < 32) {
      MFMA_STEP(h0a, h1a, l0a, l1a, P0, L0acc);
      if (st + 3 < 32) {  // refill a for step st+3
        const int off = (st + 3) * 1024;
        h0a = *(const short8*)(pSh + off);
        h1a = *(const short8*)(pSh + off + 512);
        l0a = *(const short8*)(pSl + off);
        l1a = *(const short8*)(pSl + off + 512);
      }
    }
    // Epilogue for odd step st.
    EPILOGUE(P1, L1acc, sqb);
    if (st + 2 < 32) sqb = *(const float4*)(psq + (st + 2) * 16);
    if ((st & 15) == 15) {  // finished a 256-support block (st = 15, 31)
      const int gb = split * 8 + w * 2 + (st >> 4);
#pragma unroll
      for (int t = 0; t < 4; ++t) {
        float v = bmr[t];
        v = fminf(v, __shfl_xor(v, 16, 64));
        v = fminf(v, __shfl_xor(v, 32, 64));
        if (lq == 0) bmin[(size_t)(qbase + t * 16 + lm) * NSB + gb] = v;
        bmr[t] = FLT_BIG;
      }
    }
  }
}

// ---------------------------------------------------------------------------
// Phase B: one wave per query; coalesced rescore from S_T. (Unchanged.)
__global__ __launch_bounds__(256) void k_phaseB(
    const float* __restrict__ S_T,   // [64][NTOT]
    const float* __restrict__ Q,     // [NTOT][64]
    const float* __restrict__ sqS, const float* __restrict__ bmin,
    const float* __restrict__ onehot, float* __restrict__ out) {
  __shared__ float sQrow[4][64];
  const int lane = threadIdx.x & 63;
  const int w = threadIdx.x >> 6;
  const int q = blockIdx.x * 4 + w;

  if (lane < 16)
    *(float4*)&sQrow[w][lane * 4] = *(const float4*)&Q[(size_t)q * DIM + lane * 4];
  __syncthreads();

  const float bv = bmin[(size_t)q * NSB + lane];  // lane <-> block
  float m = bv;
#pragma unroll
  for (int d = 1; d < 64; d <<= 1) m = fminf(m, __shfl_xor(m, d, 64));
  unsigned long long msk = __ballot(bv <= m + EPS);

  float bk = FLT_BIG;
  int bi = 0;
  while (msk) {  // ascending block order; wave-uniform control
    const int b = __ffsll((long long)msk) - 1;
    msk &= msk - 1;
    const int s0 = b * SBLK + lane * 4;  // 4 consecutive supports per lane
    float a0 = 0.f, a1 = 0.f, a2 = 0.f, a3 = 0.f;
#pragma unroll
    for (int c = 0; c < 16; ++c) {
      const float4 qv = *(const float4*)&sQrow[w][c * 4];  // LDS broadcast
      const float4 s0v = *(const float4*)&S_T[(size_t)(c * 4 + 0) * NTOT + s0];
      const float4 s1v = *(const float4*)&S_T[(size_t)(c * 4 + 1) * NTOT + s0];
      const float4 s2v = *(const float4*)&S_T[(size_t)(c * 4 + 2) * NTOT + s0];
      const float4 s3v = *(const float4*)&S_T[(size_t)(c * 4 + 3) * NTOT + s0];
      a0 = fmaf(qv.x, s0v.x, a0); a1 = fmaf(qv.x, s0v.y, a1);
      a2 = fmaf(qv.x, s0v.z, a2); a3 = fmaf(qv.x, s0v.w, a3);
      a0 = fmaf(qv.y, s1v.x, a0); a1 = fmaf(qv.y, s1v.y, a1);
      a2 = fmaf(qv.y, s1v.z, a2); a3 = fmaf(qv.y, s1v.w, a3);
      a0 = fmaf(qv.z, s2v.x, a0); a1 = fmaf(qv.z, s2v.y, a1);
      a2 = fmaf(qv.z, s2v.z, a2); a3 = fmaf(qv.z, s2v.w, a3);
      a0 = fmaf(qv.w, s3v.x, a0); a1 = fmaf(qv.w, s3v.y, a1);
      a2 = fmaf(qv.w, s3v.z, a2); a3 = fmaf(qv.w, s3v.w, a3);
    }
    const float4 sq4 = *(const float4*)&sqS[s0];
    const float k0 = fmaf(-2.f, a0, sq4.x);
    const float k1 = fmaf(-2.f, a1, sq4.y);
    const float k2 = fmaf(-2.f, a2, sq4.z);
    const float k3 = fmaf(-2.f, a3, sq4.w);
    bool u;  // ascending index, strict < => first minimum per lane
    u = k0 < bk; bk = u ? k0 : bk; bi = u ? s0 : bi;
    u = k1 < bk; bk = u ? k1 : bk; bi = u ? (s0 + 1) : bi;
    u = k2 < bk; bk = u ? k2 : bk; bi = u ? (s0 + 2) : bi;
    u = k3 < bk; bk = u ? k3 : bk; bi = u ? (s0 + 3) : bi;
  }
  // Cross-lane lexicographic argmin on exact keys => first-index semantics.
#pragma unroll
  for (int d = 1; d < 64; d <<= 1) {
    const float ok = __shfl_xor(bk, d, 64);
    const int oi = __shfl_xor(bi, d, 64);
    const bool u = (ok < bk) || (ok == bk && oi < bi);
    bk = u ? ok : bk;
    bi = u ? oi : bi;
  }
  // Label: one-hot rows exact {0,1}; first 1 == np.argmax.
  const float ov = onehot[(size_t)bi * 64 + lane];
  const unsigned long long lmask = __ballot(ov > 0.5f);
  const int label = __ffsll((long long)lmask) - 1;
  out[(size_t)q * 64 + lane] = (lane == label) ? 1.0f : 0.0f;
}

// ---------------------------------------------------------------------------
extern "C" void kernel_launch(void* const* d_in, const int* in_sizes, int n_in,
                              void* d_out, int out_size, void* d_ws, size_t ws_size,
                              hipStream_t stream) {
  const float* S = (const float*)d_in[0];   // [16384][64]
  const float* Q = (const float*)d_in[1];   // [16384][64]
  const float* OH = (const float*)d_in[2];  // [16384][64]
  float* out = (float*)d_out;

  char* ws = (char*)d_ws;
  ushort* Sh = (ushort*)ws;                                  // [0, 2MB)
  ushort* Sl = (ushort*)(ws + (2u << 20));                   // [2, 4MB)
  float* S_T = (float*)(ws + (4u << 20));                    // [4, 8MB)
  float* sqS = (float*)(ws + (8u << 20));                    // 64 KB
  float* bmin = (float*)(ws + (8u << 20) + (64u << 10));     // 4 MB

  k_prep<<<dim3(NTOT / 64), 256, 0, stream>>>(S, Sh, Sl, S_T, sqS);
  k_phaseA<<<dim3(8, NTOT / 64), 256, 0, stream>>>(Sh, Sl, Q, sqS, bmin);
  k_phaseB<<<dim3(NTOT / 4), 256, 0, stream>>>(S_T, Q, sqS, bmin, OH, out);
  (void)in_sizes; (void)n_in; (void)out_size; (void)ws_size;
}

// Round 10
// 189.264 us; speedup vs baseline: 1.0657x; 1.0657x over previous
//
#include <hip/hip_runtime.h>

// KNN argmin over L2, round 10.
//  - phaseA = R8's proven skeleton (panel-swizzled Sh/Sl/Qh/Ql, copy-free
//    a/b register double-buffer) with:
//      * __launch_bounds__(256,3): R8's (256,2) capped residency at 8
//        waves/CU (Occupancy 19.6%) -> joint-stall idled the MFMA pipe.
//      * single accumulator, 6-MFMA chain per tile (MFMA C-accumulation
//        chains at pipe rate; R9 disproved the dependency-split theory).
//        Epilogue: 1 fmaf per key instead of 2; 16 fewer VGPRs.
//  - k_prep: one kernel makes S panels + sqS AND Q panels (Q split once,
//    not once per split as in R9).
//  - k_transpose after phaseA (S_T aliases Sh/Sl; 12.06 MB proven layout).
//  - phaseB: unchanged exact fp32 rescore.
//
// Filter certification unchanged: 3-term split (sh.qh + sl.qh + sh.ql),
// key error <= ~0.014 << EPS=0.05 => rescore set provably contains the
// true first-argmin support. Phase B strict-< ascending + lexicographic
// cross-lane on exact fp32 keys => np.argmin first-index semantics.

#define NTOT   16384
#define DIM    64
#define SBLK   256                // bmin granularity
#define NSB    (NTOT / SBLK)      // 64
#define EPS    0.05f
#define FLT_BIG 3.4e38f

typedef __attribute__((ext_vector_type(8))) short short8;
typedef __attribute__((ext_vector_type(4))) float float4v;

__device__ __forceinline__ ushort bf16_rne(float x) {
  unsigned u = __float_as_uint(x);
  return (ushort)((u + 0x7FFF + ((u >> 16) & 1)) >> 16);
}

// ---------------------------------------------------------------------------
// Fused prep: blocks 0..255 -> S (panels + sqS); blocks 256..511 -> Q
// (panels only). Panel layout (16-row panels, phase A lane order, R8-proven):
//   off(r,k) = (r>>4)*1024 + (k>>5)*512 + (((k&31)>>3)*16 + (r&15))*8 + (k&7)
__global__ __launch_bounds__(256) void k_prep(
    const float* __restrict__ S, const float* __restrict__ Q,
    ushort* __restrict__ Sh, ushort* __restrict__ Sl,
    ushort* __restrict__ Qh, ushort* __restrict__ Ql,
    float* __restrict__ sqS) {
  __shared__ float tile[64][65];
  const int tid = threadIdx.x;
  const bool isS = blockIdx.x < 256;
  const int rbase = (blockIdx.x & 255) * 64;
  const float* __restrict__ src = isS ? S : Q;
  ushort* __restrict__ dh = isS ? Sh : Qh;
  ushort* __restrict__ dl = isS ? Sl : Ql;

  const int tx = tid & 63;
  const int ty = tid >> 6;
#pragma unroll
  for (int i = 0; i < 16; ++i) {
    const int r = i * 4 + ty;
    tile[r][tx] = src[(size_t)(rbase + r) * DIM + tx];  // coalesced
  }
  __syncthreads();

  // Panel-swizzled bf16 hi/lo; stores are lane-contiguous 16B.
  const int panel = tid >> 6;           // 0..3
  const int half = (tid >> 5) & 1;      // k-half
  const int slot0 = (tid & 31) * 2;     // slot = q8*16 + m
#pragma unroll
  for (int ss = 0; ss < 2; ++ss) {
    const int s = slot0 + ss;
    const int m = s & 15;
    const int q8 = s >> 4;
    const int row = panel * 16 + m;
    const int kb = half * 32 + q8 * 8;
    short8 hv, lv;
#pragma unroll
    for (int j = 0; j < 8; ++j) {
      const float x = tile[row][kb + j];
      const ushort h = bf16_rne(x);
      const float hf = __uint_as_float(((unsigned)h) << 16);
      hv[j] = (short)h;
      lv[j] = (short)bf16_rne(x - hf);
    }
    const size_t goff =
        (size_t)((rbase >> 4) + panel) * 1024 + (size_t)half * 512 + (size_t)s * 8;
    *(short8*)&dh[goff] = hv;
    *(short8*)&dl[goff] = lv;
  }

  if (isS && tid < 64) {
    float acc = 0.0f;
#pragma unroll
    for (int d = 0; d < DIM; ++d) {
      const float v = tile[tid][d];
      acc = fmaf(v, v, acc);
    }
    sqS[rbase + tid] = acc;
  }
}

// ---------------------------------------------------------------------------
// Transpose [NTOT][64] -> [64][NTOT]. Runs AFTER phase A (S_T aliases Sh/Sl).
__global__ __launch_bounds__(256) void k_transpose(
    const float* __restrict__ in, float* __restrict__ outT) {
  __shared__ float tile[64][65];
  const int tx = threadIdx.x & 63;
  const int ty = threadIdx.x >> 6;
  const int rbase = blockIdx.x * 64;
#pragma unroll
  for (int i = 0; i < 16; ++i) {
    const int r = i * 4 + ty;
    tile[r][tx] = in[(size_t)(rbase + r) * DIM + tx];
  }
  __syncthreads();
#pragma unroll
  for (int i = 0; i < 16; ++i) {
    const int d = i * 4 + ty;
    outT[(size_t)d * NTOT + rbase + tx] = tile[tx][d];
  }
}

// ---------------------------------------------------------------------------
// Phase A: block = 4 waves; wave w: 64 queries x 512 supports.
// grid = (8 splits, 256 q-tiles). 16x16x32 bf16 MFMA; layouts HW-verified
// R4-R9. All fragment loads lane-contiguous (panel storage).

#define MFMA16(A, B, C) __builtin_amdgcn_mfma_f32_16x16x32_bf16(A, B, C, 0, 0, 0)

// One 16-support step: 4 tiles x 6-MFMA single-acc chain (C-accumulation
// runs at pipe rate), then 1 fmaf per key + min fold.
#define STEP_COMPUTE(H0, H1, L0, L1, SQ)                                   \
  do {                                                                     \
    _Pragma("unroll")                                                      \
    for (int t = 0; t < 4; ++t) {                                          \
      float4v a = {0.f, 0.f, 0.f, 0.f};                                    \
      a = MFMA16(H0, qh[t][0], a);                                         \
      a = MFMA16(H1, qh[t][1], a);                                         \
      a = MFMA16(L0, qh[t][0], a);                                         \
      a = MFMA16(L1, qh[t][1], a);                                         \
      a = MFMA16(H0, qlo[t][0], a);                                        \
      a = MFMA16(H1, qlo[t][1], a);                                        \
      const float k0 = fmaf(-2.f, a[0], SQ.x);                             \
      const float k1 = fmaf(-2.f, a[1], SQ.y);                             \
      const float k2 = fmaf(-2.f, a[2], SQ.z);                             \
      const float k3 = fmaf(-2.f, a[3], SQ.w);                             \
      bmr[t] = fminf(bmr[t], fminf(fminf(k0, k1), fminf(k2, k3)));         \
    }                                                                      \
  } while (0)

__global__ __launch_bounds__(256, 3) void k_phaseA(
    const ushort* __restrict__ Sh, const ushort* __restrict__ Sl,
    const ushort* __restrict__ Qh, const ushort* __restrict__ Ql,
    const float* __restrict__ sqS, float* __restrict__ bmin) {
  const int tid = threadIdx.x;
  const int l = tid & 63;
  const int w = tid >> 6;
  const int lm = l & 15;
  const int lq = l >> 4;
  const int split = blockIdx.x;       // 0..7
  const int qbase = blockIdx.y * 64;
  const int sbase = split * 2048 + w * 512;

  // Query (B) fragments, hi and lo: 4 tiles x 2 k-chunks. Lane-contiguous.
  short8 qh[4][2], qlo[4][2];
#pragma unroll
  for (int t = 0; t < 4; ++t) {
    const size_t pb = (size_t)((qbase >> 4) + t) * 1024 + (size_t)l * 8;
    qh[t][0] = *(const short8*)&Qh[pb];
    qh[t][1] = *(const short8*)&Qh[pb + 512];
    qlo[t][0] = *(const short8*)&Ql[pb];
    qlo[t][1] = *(const short8*)&Ql[pb + 512];
  }

  const ushort* pSh = Sh + (size_t)(sbase >> 4) * 1024 + (size_t)l * 8;
  const ushort* pSl = Sl + (size_t)(sbase >> 4) * 1024 + (size_t)l * 8;
  const float* psq = sqS + sbase + lq * 4;

  // Copy-free double buffer: even steps use (a), odd steps use (b).
  short8 h0a = *(const short8*)(pSh);
  short8 h1a = *(const short8*)(pSh + 512);
  short8 l0a = *(const short8*)(pSl);
  short8 l1a = *(const short8*)(pSl + 512);
  float4 sqa = *(const float4*)(psq);
  short8 h0b = *(const short8*)(pSh + 1024);
  short8 h1b = *(const short8*)(pSh + 1024 + 512);
  short8 l0b = *(const short8*)(pSl + 1024);
  short8 l1b = *(const short8*)(pSl + 1024 + 512);
  float4 sqb = *(const float4*)(psq + 16);

  float bmr[4] = {FLT_BIG, FLT_BIG, FLT_BIG, FLT_BIG};

  for (int st = 0; st < 32; st += 2) {
    STEP_COMPUTE(h0a, h1a, l0a, l1a, sqa);
    if (st + 2 < 32) {
      const int off = (st + 2) * 1024;
      h0a = *(const short8*)(pSh + off);
      h1a = *(const short8*)(pSh + off + 512);
      l0a = *(const short8*)(pSl + off);
      l1a = *(const short8*)(pSl + off + 512);
      sqa = *(const float4*)(psq + (st + 2) * 16);
    }
    STEP_COMPUTE(h0b, h1b, l0b, l1b, sqb);
    if (st + 3 < 32) {
      const int off = (st + 3) * 1024;
      h0b = *(const short8*)(pSh + off);
      h1b = *(const short8*)(pSh + off + 512);
      l0b = *(const short8*)(pSl + off);
      l1b = *(const short8*)(pSl + off + 512);
      sqb = *(const float4*)(psq + (st + 3) * 16);
    }
    if (((st + 1) & 15) == 15) {  // finished a 256-support block
      const int gb = split * 8 + w * 2 + ((st + 1) >> 4);
#pragma unroll
      for (int t = 0; t < 4; ++t) {
        float v = bmr[t];
        v = fminf(v, __shfl_xor(v, 16, 64));
        v = fminf(v, __shfl_xor(v, 32, 64));
        if (lq == 0) bmin[(size_t)(qbase + t * 16 + lm) * NSB + gb] = v;
        bmr[t] = FLT_BIG;
      }
    }
  }
}

// ---------------------------------------------------------------------------
// Phase B: one wave per query; coalesced rescore from S_T. (Unchanged.)
__global__ __launch_bounds__(256) void k_phaseB(
    const float* __restrict__ S_T,   // [64][NTOT]
    const float* __restrict__ Q,     // [NTOT][64]
    const float* __restrict__ sqS, const float* __restrict__ bmin,
    const float* __restrict__ onehot, float* __restrict__ out) {
  __shared__ float sQrow[4][64];
  const int lane = threadIdx.x & 63;
  const int w = threadIdx.x >> 6;
  const int q = blockIdx.x * 4 + w;

  if (lane < 16)
    *(float4*)&sQrow[w][lane * 4] = *(const float4*)&Q[(size_t)q * DIM + lane * 4];
  __syncthreads();

  const float bv = bmin[(size_t)q * NSB + lane];  // lane <-> block
  float m = bv;
#pragma unroll
  for (int d = 1; d < 64; d <<= 1) m = fminf(m, __shfl_xor(m, d, 64));
  unsigned long long msk = __ballot(bv <= m + EPS);

  float bk = FLT_BIG;
  int bi = 0;
  while (msk) {  // ascending block order; wave-uniform control
    const int b = __ffsll((long long)msk) - 1;
    msk &= msk - 1;
    const int s0 = b * SBLK + lane * 4;  // 4 consecutive supports per lane
    float a0 = 0.f, a1 = 0.f, a2 = 0.f, a3 = 0.f;
#pragma unroll
    for (int c = 0; c < 16; ++c) {
      const float4 qv = *(const float4*)&sQrow[w][c * 4];  // LDS broadcast
      const float4 s0v = *(const float4*)&S_T[(size_t)(c * 4 + 0) * NTOT + s0];
      const float4 s1v = *(const float4*)&S_T[(size_t)(c * 4 + 1) * NTOT + s0];
      const float4 s2v = *(const float4*)&S_T[(size_t)(c * 4 + 2) * NTOT + s0];
      const float4 s3v = *(const float4*)&S_T[(size_t)(c * 4 + 3) * NTOT + s0];
      a0 = fmaf(qv.x, s0v.x, a0); a1 = fmaf(qv.x, s0v.y, a1);
      a2 = fmaf(qv.x, s0v.z, a2); a3 = fmaf(qv.x, s0v.w, a3);
      a0 = fmaf(qv.y, s1v.x, a0); a1 = fmaf(qv.y, s1v.y, a1);
      a2 = fmaf(qv.y, s1v.z, a2); a3 = fmaf(qv.y, s1v.w, a3);
      a0 = fmaf(qv.z, s2v.x, a0); a1 = fmaf(qv.z, s2v.y, a1);
      a2 = fmaf(qv.z, s2v.z, a2); a3 = fmaf(qv.z, s2v.w, a3);
      a0 = fmaf(qv.w, s3v.x, a0); a1 = fmaf(qv.w, s3v.y, a1);
      a2 = fmaf(qv.w, s3v.z, a2); a3 = fmaf(qv.w, s3v.w, a3);
    }
    const float4 sq4 = *(const float4*)&sqS[s0];
    const float k0 = fmaf(-2.f, a0, sq4.x);
    const float k1 = fmaf(-2.f, a1, sq4.y);
    const float k2 = fmaf(-2.f, a2, sq4.z);
    const float k3 = fmaf(-2.f, a3, sq4.w);
    bool u;  // ascending index, strict < => first minimum per lane
    u = k0 < bk; bk = u ? k0 : bk; bi = u ? s0 : bi;
    u = k1 < bk; bk = u ? k1 : bk; bi = u ? (s0 + 1) : bi;
    u = k2 < bk; bk = u ? k2 : bk; bi = u ? (s0 + 2) : bi;
    u = k3 < bk; bk = u ? k3 : bk; bi = u ? (s0 + 3) : bi;
  }
  // Cross-lane lexicographic argmin on exact keys => first-index semantics.
#pragma unroll
  for (int d = 1; d < 64; d <<= 1) {
    const float ok = __shfl_xor(bk, d, 64);
    const int oi = __shfl_xor(bi, d, 64);
    const bool u = (ok < bk) || (ok == bk && oi < bi);
    bk = u ? ok : bk;
    bi = u ? oi : bi;
  }
  // Label: one-hot rows exact {0,1}; first 1 == np.argmax.
  const float ov = onehot[(size_t)bi * 64 + lane];
  const unsigned long long lmask = __ballot(ov > 0.5f);
  const int label = __ffsll((long long)lmask) - 1;
  out[(size_t)q * 64 + lane] = (lane == label) ? 1.0f : 0.0f;
}

// ---------------------------------------------------------------------------
extern "C" void kernel_launch(void* const* d_in, const int* in_sizes, int n_in,
                              void* d_out, int out_size, void* d_ws, size_t ws_size,
                              hipStream_t stream) {
  const float* S = (const float*)d_in[0];   // [16384][64]
  const float* Q = (const float*)d_in[1];   // [16384][64]
  const float* OH = (const float*)d_in[2];  // [16384][64]
  float* out = (float*)d_out;

  char* ws = (char*)d_ws;
  ushort* Sh = (ushort*)ws;                                  // [0, 2MB)
  ushort* Sl = (ushort*)(ws + (2u << 20));                   // [2, 4MB)
  ushort* Qh = (ushort*)(ws + (4u << 20));                   // [4, 6MB)
  ushort* Ql = (ushort*)(ws + (6u << 20));                   // [6, 8MB)
  float* S_T = (float*)ws;                                   // aliases Sh+Sl
  float* sqS = (float*)(ws + (8u << 20));                    // 64 KB
  float* bmin = (float*)(ws + (8u << 20) + (64u << 10));     // 4 MB

  k_prep<<<dim3(512), 256, 0, stream>>>(S, Q, Sh, Sl, Qh, Ql, sqS);
  k_phaseA<<<dim3(8, NTOT / 64), 256, 0, stream>>>(Sh, Sl, Qh, Ql, sqS, bmin);
  k_transpose<<<dim3(NTOT / 64), 256, 0, stream>>>(S, S_T);  // after phaseA
  k_phaseB<<<dim3(NTOT / 4), 256, 0, stream>>>(S_T, Q, sqS, bmin, OH, out);
  (void)in_sizes; (void)n_in; (void)out_size; (void)ws_size;
}